// Round 1
// baseline (527.421 us; speedup 1.0000x reference)
//
#include <hip/hip_runtime.h>

// EmbeddingBagCollection: F tables [N,D] fp32, jagged sum-pool per bag.
// out[b, f*D + d] = sum_{i in [offs[f][b], offs[f][b+1])} tables[f][values[f][i]][d]
#define F_TABLES 8
#define B_BAGS   8192
#define N_ROWS   200000
#define D_DIM    64
#define T_IDX    163840

// One wave per 4 CONSECUTIVE bags of one feature. Offsets are cumulative, so
// the 4 bags cover one contiguous range of `values` -> wave-uniform loop
// bounds with ~2x the load-slot utilization of bag-per-wave (avg bag len 20).
// Inner loop is branch-free: unconditional row loads (dead slots read row 0,
// which stays L1-hot -> ~zero extra DRAM traffic) and per-bag mask-FMA
// accumulation into 4 float4 accumulators. Step guards (rb+4*jj < e) are
// wave-uniform -> scalar branches, no divergence.
__global__ __launch_bounds__(256, 6) void ebc_pool_kernel(
    const float* __restrict__ tables,
    const int*   __restrict__ values,
    const int*   __restrict__ offsets,
    float*       __restrict__ out)
{
    const int wave = blockIdx.x * (blockDim.x >> 6) + (threadIdx.x >> 6);
    const int lane = threadIdx.x & 63;
    const int g    = lane >> 4;        // row-group 0..3
    const int c    = lane & 15;        // float4 chunk within row

    const int f  = wave >> 11;         // 2048 waves per feature
    const int b0 = (wave & 2047) << 2; // first of this wave's 4 bags

    const float4* __restrict__ tab =
        (const float4*)(tables + (size_t)f * N_ROWS * D_DIM);
    const int* __restrict__ vals = values + f * T_IDX;

    // one coalesced 20B txn for the 5 offsets, then broadcast
    const int obase = f * (B_BAGS + 1) + b0;
    int oo = 0;
    if (lane < 5) oo = offsets[obase + lane];
    const int s0 = __shfl(oo, 0, 64);
    const int o1 = __shfl(oo, 1, 64);
    const int o2 = __shfl(oo, 2, 64);
    const int o3 = __shfl(oo, 3, 64);
    const int e  = __shfl(oo, 4, 64);

    float4 a0 = make_float4(0.f, 0.f, 0.f, 0.f);
    float4 a1 = make_float4(0.f, 0.f, 0.f, 0.f);
    float4 a2 = make_float4(0.f, 0.f, 0.f, 0.f);
    float4 a3 = make_float4(0.f, 0.f, 0.f, 0.f);

    for (int rb = s0; rb < e; rb += 64) {
        int myidx = 0;
        if (rb + lane < e) myidx = vals[rb + lane];   // coalesced idx fetch
        #pragma unroll
        for (int jj = 0; jj < 16; ++jj) {
            if (rb + jj * 4 < e) {                    // wave-uniform guard
                const int pos = jj * 4 + g;           // group g takes pos%4==g
                const int gi  = rb + pos;             // global index position
                const int idx = __shfl(myidx, pos, 64); // 0 for dead slots
                const float4 v = tab[(size_t)idx * (D_DIM / 4) + c];
                // bag-select masks (group-uniform, branch-free)
                const float m0 = (gi < o1)              ? 1.f : 0.f;
                const float m1 = (gi >= o1 && gi < o2)  ? 1.f : 0.f;
                const float m2 = (gi >= o2 && gi < o3)  ? 1.f : 0.f;
                const float m3 = (gi >= o3 && gi < e)   ? 1.f : 0.f;
                a0.x = fmaf(v.x, m0, a0.x); a0.y = fmaf(v.y, m0, a0.y);
                a0.z = fmaf(v.z, m0, a0.z); a0.w = fmaf(v.w, m0, a0.w);
                a1.x = fmaf(v.x, m1, a1.x); a1.y = fmaf(v.y, m1, a1.y);
                a1.z = fmaf(v.z, m1, a1.z); a1.w = fmaf(v.w, m1, a1.w);
                a2.x = fmaf(v.x, m2, a2.x); a2.y = fmaf(v.y, m2, a2.y);
                a2.z = fmaf(v.z, m2, a2.z); a2.w = fmaf(v.w, m2, a2.w);
                a3.x = fmaf(v.x, m3, a3.x); a3.y = fmaf(v.y, m3, a3.y);
                a3.z = fmaf(v.z, m3, a3.z); a3.w = fmaf(v.w, m3, a3.w);
            }
        }
    }

    // fold the 4 group-partials (lanes c, c+16, c+32, c+48 hold same dims)
    #pragma unroll
    for (int m = 16; m < 64; m <<= 1) {
        a0.x += __shfl_xor(a0.x, m, 64); a0.y += __shfl_xor(a0.y, m, 64);
        a0.z += __shfl_xor(a0.z, m, 64); a0.w += __shfl_xor(a0.w, m, 64);
        a1.x += __shfl_xor(a1.x, m, 64); a1.y += __shfl_xor(a1.y, m, 64);
        a1.z += __shfl_xor(a1.z, m, 64); a1.w += __shfl_xor(a1.w, m, 64);
        a2.x += __shfl_xor(a2.x, m, 64); a2.y += __shfl_xor(a2.y, m, 64);
        a2.z += __shfl_xor(a2.z, m, 64); a2.w += __shfl_xor(a2.w, m, 64);
        a3.x += __shfl_xor(a3.x, m, 64); a3.y += __shfl_xor(a3.y, m, 64);
        a3.z += __shfl_xor(a3.z, m, 64); a3.w += __shfl_xor(a3.w, m, 64);
    }

    // every lane now holds full sums for all 4 bags; group g stores bag g
    float4 res = a3;
    if (g == 2) res = a2;
    if (g == 1) res = a1;
    if (g == 0) res = a0;
    float4* o = (float4*)(out + (size_t)(b0 + g) * (F_TABLES * D_DIM) + f * D_DIM);
    o[c] = res;
}

extern "C" void kernel_launch(void* const* d_in, const int* in_sizes, int n_in,
                              void* d_out, int out_size, void* d_ws, size_t ws_size,
                              hipStream_t stream) {
    const float* tables  = (const float*)d_in[0];
    const int*   values  = (const int*)d_in[1];
    const int*   offsets = (const int*)d_in[2];
    float*       out     = (float*)d_out;

    // F*B/4 = 16384 waves, 4 waves per 256-thread block -> 4096 blocks
    const int blocks = (F_TABLES * B_BAGS) / (4 * 4);
    hipLaunchKernelGGL(ebc_pool_kernel, dim3(blocks), dim3(256), 0, stream,
                       tables, values, offsets, out);
}